// Round 2
// baseline (346.506 us; speedup 1.0000x reference)
//
#include <hip/hip_runtime.h>
#include <math.h>

#define NB 32            // batch
#define DET_BLOCKS 96    // 3 scales * 32 images (det-only blocks)
#define SEG_BLOCKS 2048  // seg blocks, 1024 quads each (64 blocks per image)
#define TOTAL_BLOCKS (DET_BLOCKS + SEG_BLOCKS)

// monotonically-increasing completion ticket (survives graph replays; each
// launch adds exactly TOTAL_BLOCKS, so (old+1) % TOTAL_BLOCKS == 0 marks the
// last block of *this* launch)
__device__ unsigned int g_done = 0u;

// ---------- math helpers (match reference semantics) ----------

__device__ __forceinline__ float bce_logits(float x, float y) {
    // max(x,0) - x*y + log1p(exp(-|x|))
    float a = fabsf(x);
    return fmaxf(x, 0.f) - x * y + __logf(1.f + __expf(-a));
}

__device__ __forceinline__ float focal_elt(float x, float t) {
    // t is exactly 0.0 or 1.0 (one-hot)
    float p = 1.f / (1.f + __expf(-x));
    float ce = bce_logits(x, t);
    float p_t = (t > 0.5f) ? p : (1.f - p);
    float a_t = (t > 0.5f) ? 0.25f : 0.75f;
    float om = 1.f - p_t;
    return a_t * om * om * ce;
}

// Block reduction for N floats, blockDim.x == 256 (4 waves of 64).
template <int N>
__device__ void blk_reduce_arr(float* v) {
    __shared__ float sm[N][4];
    int lane = threadIdx.x & 63;
    int wid  = threadIdx.x >> 6;
#pragma unroll
    for (int j = 0; j < N; j++) {
        float x = v[j];
#pragma unroll
        for (int off = 32; off > 0; off >>= 1) x += __shfl_down(x, off, 64);
        if (lane == 0) sm[j][wid] = x;
    }
    __syncthreads();
    if (threadIdx.x == 0) {
#pragma unroll
        for (int j = 0; j < N; j++) {
            float s = 0.f;
#pragma unroll
            for (int w = 0; w < 4; w++) s += sm[j][w];
            v[j] = s;
        }
    }
}

// ---------- fully fused: det + seg + last-block final reduce ----------

__global__ __launch_bounds__(256) void fused_kernel(
        const float* __restrict__ seg_logits, const int* __restrict__ mask,
        const float* __restrict__ cls0, const float* __restrict__ cls1, const float* __restrict__ cls2,
        const float* __restrict__ reg0, const float* __restrict__ reg1, const float* __restrict__ reg2,
        const float* __restrict__ cen0, const float* __restrict__ cen1, const float* __restrict__ cen2,
        const float* __restrict__ boxes, const int* __restrict__ labels,
        const float* __restrict__ cls_pred, const int* __restrict__ cls_target,
        float* __restrict__ segpart, float* __restrict__ detc,
        float* __restrict__ out) {

    __shared__ int last_flag;

    if (blockIdx.x < DET_BLOCKS) {
        // ===== det block: one (scale, image) =====
        const int s = blockIdx.x >> 5;   // 0..2
        const int b = blockIdx.x & 31;   // 0..31
        int Wd, shift, L; float stride;
        const float *cls, *reg, *cen;
        if (s == 0)      { Wd = 64; shift = 6; L = 4096; stride = 8.f;  cls = cls0; reg = reg0; cen = cen0; }
        else if (s == 1) { Wd = 32; shift = 5; L = 1024; stride = 16.f; cls = cls1; reg = reg1; cen = cen1; }
        else             { Wd = 16; shift = 4; L = 256;  stride = 32.f; cls = cls2; reg = reg2; cen = cen2; }

        __shared__ float sx0[20], sy0[20], sx1[20], sy1[20], sar[20];
        __shared__ int   slb[20];
        if (threadIdx.x < 20) {
            int k = threadIdx.x;
            const float* bb = boxes + (b * 20 + k) * 4;
            float cx = bb[0] * 512.f, cy = bb[1] * 512.f;
            float w  = bb[2] * 512.f, h  = bb[3] * 512.f;
            float x0 = cx - 0.5f * w, y0 = cy - 0.5f * h;
            float x1 = cx + 0.5f * w, y1 = cy + 0.5f * h;
            sx0[k] = x0; sy0[k] = y0; sx1[k] = x1; sy1[k] = y1;
            sar[k] = (x1 - x0) * (y1 - y0);
            slb[k] = labels[b * 20 + k];
        }
        __syncthreads();

        const float* clsb = cls + (size_t)b * 5 * L;
        const float* regb = reg + (size_t)b * 4 * L;
        const float* cenb = cen + (size_t)b * L;
        const float inv = 1.f / stride;

        float cls_s = 0.f, reg_s = 0.f, cen_s = 0.f, np = 0.f;
        for (int l = threadIdx.x; l < L; l += 256) {
            float lx = ((l & (Wd - 1)) + 0.5f) * stride;
            float ly = ((l >> shift)   + 0.5f) * stride;
            int bk = -1; float ba = INFINITY;
            float bl = 0.f, btp = 0.f, brr = 0.f, bbt = 0.f;
#pragma unroll
            for (int k = 0; k < 20; k++) {
                float li = lx - sx0[k], ti = ly - sy0[k];
                float ri = sx1[k] - lx, bi = sy1[k] - ly;
                float mn = fminf(fminf(li, ti), fminf(ri, bi));
                if (mn > 0.f && sar[k] < ba) {   // strict '<' == first-occurrence argmin
                    ba = sar[k]; bk = k;
                    bl = li; btp = ti; brr = ri; bbt = bi;
                }
            }
            int tl = (bk >= 0) ? slb[bk] : -1;
#pragma unroll
            for (int c = 0; c < 4; c++) {
                float x = clsb[(c + 1) * L + l];   // channel 0 dropped by reference
                cls_s += focal_elt(x, (c == tl) ? 1.f : 0.f);
            }
            if (bk >= 0) {
                float r0 = bl * inv, r1 = btp * inv, r2 = brr * inv, r3 = bbt * inv;
                float d0 = regb[0 * L + l] - r0;
                float d1 = regb[1 * L + l] - r1;
                float d2 = regb[2 * L + l] - r2;
                float d3 = regb[3 * L + l] - r3;
                float a0 = fabsf(d0), a1 = fabsf(d1), a2 = fabsf(d2), a3 = fabsf(d3);
                float sl = (a0 < 1.f ? 0.5f * d0 * d0 : a0 - 0.5f)
                         + (a1 < 1.f ? 0.5f * d1 * d1 : a1 - 0.5f)
                         + (a2 < 1.f ? 0.5f * d2 * d2 : a2 - 0.5f)
                         + (a3 < 1.f ? 0.5f * d3 * d3 : a3 - 0.5f);
                reg_s += 0.25f * sl;
                float mnlr = fminf(r0, r2), mxlr = fmaxf(r0, r2);
                float mntb = fminf(r1, r3), mxtb = fmaxf(r1, r3);
                float v = (mnlr / (mxlr + 1e-6f)) * (mntb / (mxtb + 1e-6f));
                v = fminf(fmaxf(v, 0.f), 1.f);
                float ct = sqrtf(v);
                cen_s += bce_logits(cenb[l], ct);
                np += 1.f;
            }
        }

        float v4[4] = {cls_s, reg_s, cen_s, np};
        blk_reduce_arr<4>(v4);
        if (threadIdx.x == 0) {
            float cls_l = v4[0] / (L * 4.f);
            float npos  = v4[3];
            float denom = fmaxf(npos, 1.f);
            float reg_l = (npos > 0.f) ? v4[1] / denom : 0.f;
            float cen_l = (npos > 0.f) ? v4[2] / denom : 0.f;
            detc[blockIdx.x] = (cls_l + reg_l + cen_l) * (1.f / (float)DET_BLOCKS);
        }
    } else {
        // ===== seg block: 1024 quads, ALL 20 loads issued before any compute =====
        // Pure stream, no reuse -> no LDS. MLP is the lever: 20 dwordx4 loads
        // in flight per thread (vs ~5-10 in previous rounds).
        const int HW  = 512 * 512;     // px per image
        const int QPI = HW / 4;        // 65536 quads per image
        const int sblk = blockIdx.x - DET_BLOCKS;      // 0..2047
        const size_t qbase = (size_t)sblk * 1024;      // 64 blocks/image, no straddle
        const int b  = (int)(qbase >> 16);             // image index
        const int qs = (int)(qbase & 65535);           // start quad within image
        const int t  = threadIdx.x;

        const int4*   mq = (const int4*)(mask + (size_t)b * HW) + qs;
        const float4* xq = (const float4*)(seg_logits + (size_t)b * 4 * HW) + qs;

        int4   m[4];
        float4 a0[4], a1[4], a2[4], a3[4];
        // load phase: 20 independent global_load_dwordx4, fully unrolled
        // (static indices after unroll -> registers, not scratch)
#pragma unroll
        for (int j = 0; j < 4; j++) {
            const int idx = j * 256 + t;
            m[j]  = mq[idx];
            a0[j] = xq[0 * QPI + idx];
            a1[j] = xq[1 * QPI + idx];
            a2[j] = xq[2 * QPI + idx];
            a3[j] = xq[3 * QPI + idx];
        }
        // compute phase
        float acc = 0.f;
#pragma unroll
        for (int j = 0; j < 4; j++) {
            const float t0 = (float)m[j].x, t1 = (float)m[j].y;
            const float t2 = (float)m[j].z, t3 = (float)m[j].w;
            acc += bce_logits(a0[j].x, t0) + bce_logits(a0[j].y, t1)
                 + bce_logits(a0[j].z, t2) + bce_logits(a0[j].w, t3);
            acc += bce_logits(a1[j].x, t0) + bce_logits(a1[j].y, t1)
                 + bce_logits(a1[j].z, t2) + bce_logits(a1[j].w, t3);
            acc += bce_logits(a2[j].x, t0) + bce_logits(a2[j].y, t1)
                 + bce_logits(a2[j].z, t2) + bce_logits(a2[j].w, t3);
            acc += bce_logits(a3[j].x, t0) + bce_logits(a3[j].y, t1)
                 + bce_logits(a3[j].z, t2) + bce_logits(a3[j].w, t3);
        }

        float v[1] = {acc};
        blk_reduce_arr<1>(v);
        if (threadIdx.x == 0) segpart[sblk] = v[0];
    }

    // ===== completion: last block of this launch does the final combine =====
    if (threadIdx.x == 0) {
        __threadfence();                              // release partial write
        unsigned old = atomicAdd(&g_done, 1u);        // device-scope
        last_flag = ((old + 1u) % (unsigned)TOTAL_BLOCKS == 0u) ? 1 : 0;
    }
    __syncthreads();

    if (last_flag) {
        __threadfence();                              // acquire all partials
        const float seg_scale = 1.f / 33554432.f;     // B*4*512*512 (2^-25, exact)
        const float cls_scale = 0.5f / 320.f;         // W_CLS / (B*10)
        float acc = 0.f;
        for (int i = threadIdx.x; i < SEG_BLOCKS; i += 256) acc += segpart[i] * seg_scale;
        if (threadIdx.x < DET_BLOCKS) acc += detc[threadIdx.x];
        for (int e = threadIdx.x; e < NB * 10; e += 256) {
            int i = e / 10, c = e - i * 10;
            acc += cls_scale * focal_elt(cls_pred[e], (cls_target[i] == c) ? 1.f : 0.f);
        }
        float v[1] = {acc};
        blk_reduce_arr<1>(v);
        if (threadIdx.x == 0) out[0] = v[0];
    }
}

// ---------- launch ----------

extern "C" void kernel_launch(void* const* d_in, const int* in_sizes, int n_in,
                              void* d_out, int out_size, void* d_ws, size_t ws_size,
                              hipStream_t stream) {
    const float* seg_logits = (const float*)d_in[0];
    const int*   seg_mask   = (const int*)d_in[1];
    const float* cls0 = (const float*)d_in[2];
    const float* cls1 = (const float*)d_in[3];
    const float* cls2 = (const float*)d_in[4];
    const float* reg0 = (const float*)d_in[5];
    const float* reg1 = (const float*)d_in[6];
    const float* reg2 = (const float*)d_in[7];
    const float* cen0 = (const float*)d_in[8];
    const float* cen1 = (const float*)d_in[9];
    const float* cen2 = (const float*)d_in[10];
    const float* boxes  = (const float*)d_in[11];
    const int*   labels = (const int*)d_in[12];
    const float* cls_pred   = (const float*)d_in[13];
    const int*   cls_target = (const int*)d_in[14];

    float* ws      = (float*)d_ws;
    float* segpart = ws;                 // SEG_BLOCKS floats
    float* detc    = ws + SEG_BLOCKS;    // DET_BLOCKS floats

    fused_kernel<<<TOTAL_BLOCKS, 256, 0, stream>>>(seg_logits, seg_mask,
                                                   cls0, cls1, cls2,
                                                   reg0, reg1, reg2,
                                                   cen0, cen1, cen2,
                                                   boxes, labels,
                                                   cls_pred, cls_target,
                                                   segpart, detc,
                                                   (float*)d_out);
}

// Round 3
// 291.254 us; speedup vs baseline: 1.1897x; 1.1897x over previous
//
#include <hip/hip_runtime.h>
#include <math.h>

#define NB 32            // batch
#define DET_BLOCKS 96    // 3 scales * 32 images
#define SEG_BLOCKS 2048  // 1024 quads each (64 blocks per image), 8 blocks/CU

// ---------- math helpers (match reference semantics) ----------

__device__ __forceinline__ float bce_logits(float x, float y) {
    // max(x,0) - x*y + log1p(exp(-|x|))
    float a = fabsf(x);
    return fmaxf(x, 0.f) - x * y + __logf(1.f + __expf(-a));
}

__device__ __forceinline__ float focal_elt(float x, float t) {
    // t is exactly 0.0 or 1.0 (one-hot)
    float p = 1.f / (1.f + __expf(-x));
    float ce = bce_logits(x, t);
    float p_t = (t > 0.5f) ? p : (1.f - p);
    float a_t = (t > 0.5f) ? 0.25f : 0.75f;
    float om = 1.f - p_t;
    return a_t * om * om * ce;
}

// Block reduction for N floats, blockDim.x == 256 (4 waves of 64).
template <int N>
__device__ void blk_reduce_arr(float* v) {
    __shared__ float sm[N][4];
    int lane = threadIdx.x & 63;
    int wid  = threadIdx.x >> 6;
#pragma unroll
    for (int j = 0; j < N; j++) {
        float x = v[j];
#pragma unroll
        for (int off = 32; off > 0; off >>= 1) x += __shfl_down(x, off, 64);
        if (lane == 0) sm[j][wid] = x;
    }
    __syncthreads();
    if (threadIdx.x == 0) {
#pragma unroll
        for (int j = 0; j < N; j++) {
            float s = 0.f;
#pragma unroll
            for (int w = 0; w < 4; w++) s += sm[j][w];
            v[j] = s;
        }
    }
}

// ---------- seg: standalone streaming kernel, occupancy-first ----------
// __launch_bounds__(256, 8): 8 waves/EU -> register allocator must fit 64
// VGPR -> up to 8 blocks/CU = 32 waves/CU. Grid = 2048 = exactly 8 per CU.
// Seg loop alone needs ~40-55 VGPR; fusing it with det (VGPR 84) was capping
// the streaming phase's occupancy.

__global__ __launch_bounds__(256, 8) void seg_kernel(
        const float* __restrict__ seg_logits, const int* __restrict__ mask,
        float* __restrict__ segpart) {
    const int HW  = 512 * 512;     // px per image
    const int QPI = HW / 4;        // 65536 quads per image
    const int sblk = blockIdx.x;                   // 0..2047
    const size_t qbase = (size_t)sblk * 1024;      // 64 blocks/image, no straddle
    const int b  = (int)(qbase >> 16);             // image index
    const int qs = (int)(qbase & 65535);           // start quad within image
    const int t  = threadIdx.x;

    const int4*   mq = (const int4*)(mask + (size_t)b * HW) + qs;
    const float4* xq = (const float4*)(seg_logits + (size_t)b * 4 * HW) + qs;

    float acc = 0.f;
#pragma unroll 2
    for (int j = 0; j < 4; j++) {
        const int idx = j * 256 + t;
        const int4   m  = mq[idx];
        const float4 x0 = xq[0 * QPI + idx];
        const float4 x1 = xq[1 * QPI + idx];
        const float4 x2 = xq[2 * QPI + idx];
        const float4 x3 = xq[3 * QPI + idx];
        const float t0 = (float)m.x, t1 = (float)m.y;
        const float t2 = (float)m.z, t3 = (float)m.w;
        acc += bce_logits(x0.x, t0) + bce_logits(x0.y, t1)
             + bce_logits(x0.z, t2) + bce_logits(x0.w, t3);
        acc += bce_logits(x1.x, t0) + bce_logits(x1.y, t1)
             + bce_logits(x1.z, t2) + bce_logits(x1.w, t3);
        acc += bce_logits(x2.x, t0) + bce_logits(x2.y, t1)
             + bce_logits(x2.z, t2) + bce_logits(x2.w, t3);
        acc += bce_logits(x3.x, t0) + bce_logits(x3.y, t1)
             + bce_logits(x3.z, t2) + bce_logits(x3.w, t3);
    }

    float v[1] = {acc};
    blk_reduce_arr<1>(v);
    if (threadIdx.x == 0) segpart[sblk] = v[0];
}

// ---------- det: standalone, register allocation unconstrained ----------

__global__ __launch_bounds__(256) void det_kernel(
        const float* __restrict__ cls0, const float* __restrict__ cls1, const float* __restrict__ cls2,
        const float* __restrict__ reg0, const float* __restrict__ reg1, const float* __restrict__ reg2,
        const float* __restrict__ cen0, const float* __restrict__ cen1, const float* __restrict__ cen2,
        const float* __restrict__ boxes, const int* __restrict__ labels,
        float* __restrict__ detc) {
    const int s = blockIdx.x >> 5;   // 0..2
    const int b = blockIdx.x & 31;   // 0..31
    int Wd, shift, L; float stride;
    const float *cls, *reg, *cen;
    if (s == 0)      { Wd = 64; shift = 6; L = 4096; stride = 8.f;  cls = cls0; reg = reg0; cen = cen0; }
    else if (s == 1) { Wd = 32; shift = 5; L = 1024; stride = 16.f; cls = cls1; reg = reg1; cen = cen1; }
    else             { Wd = 16; shift = 4; L = 256;  stride = 32.f; cls = cls2; reg = reg2; cen = cen2; }

    __shared__ float sx0[20], sy0[20], sx1[20], sy1[20], sar[20];
    __shared__ int   slb[20];
    if (threadIdx.x < 20) {
        int k = threadIdx.x;
        const float* bb = boxes + (b * 20 + k) * 4;
        float cx = bb[0] * 512.f, cy = bb[1] * 512.f;
        float w  = bb[2] * 512.f, h  = bb[3] * 512.f;
        float x0 = cx - 0.5f * w, y0 = cy - 0.5f * h;
        float x1 = cx + 0.5f * w, y1 = cy + 0.5f * h;
        sx0[k] = x0; sy0[k] = y0; sx1[k] = x1; sy1[k] = y1;
        sar[k] = (x1 - x0) * (y1 - y0);
        slb[k] = labels[b * 20 + k];
    }
    __syncthreads();

    const float* clsb = cls + (size_t)b * 5 * L;
    const float* regb = reg + (size_t)b * 4 * L;
    const float* cenb = cen + (size_t)b * L;
    const float inv = 1.f / stride;

    float cls_s = 0.f, reg_s = 0.f, cen_s = 0.f, np = 0.f;
    for (int l = threadIdx.x; l < L; l += 256) {
        float lx = ((l & (Wd - 1)) + 0.5f) * stride;
        float ly = ((l >> shift)   + 0.5f) * stride;
        int bk = -1; float ba = INFINITY;
        float bl = 0.f, btp = 0.f, brr = 0.f, bbt = 0.f;
#pragma unroll
        for (int k = 0; k < 20; k++) {
            float li = lx - sx0[k], ti = ly - sy0[k];
            float ri = sx1[k] - lx, bi = sy1[k] - ly;
            float mn = fminf(fminf(li, ti), fminf(ri, bi));
            if (mn > 0.f && sar[k] < ba) {   // strict '<' == first-occurrence argmin
                ba = sar[k]; bk = k;
                bl = li; btp = ti; brr = ri; bbt = bi;
            }
        }
        int tl = (bk >= 0) ? slb[bk] : -1;
#pragma unroll
        for (int c = 0; c < 4; c++) {
            float x = clsb[(c + 1) * L + l];   // channel 0 dropped by reference
            cls_s += focal_elt(x, (c == tl) ? 1.f : 0.f);
        }
        if (bk >= 0) {
            float r0 = bl * inv, r1 = btp * inv, r2 = brr * inv, r3 = bbt * inv;
            float d0 = regb[0 * L + l] - r0;
            float d1 = regb[1 * L + l] - r1;
            float d2 = regb[2 * L + l] - r2;
            float d3 = regb[3 * L + l] - r3;
            float a0 = fabsf(d0), a1 = fabsf(d1), a2 = fabsf(d2), a3 = fabsf(d3);
            float sl = (a0 < 1.f ? 0.5f * d0 * d0 : a0 - 0.5f)
                     + (a1 < 1.f ? 0.5f * d1 * d1 : a1 - 0.5f)
                     + (a2 < 1.f ? 0.5f * d2 * d2 : a2 - 0.5f)
                     + (a3 < 1.f ? 0.5f * d3 * d3 : a3 - 0.5f);
            reg_s += 0.25f * sl;
            float mnlr = fminf(r0, r2), mxlr = fmaxf(r0, r2);
            float mntb = fminf(r1, r3), mxtb = fmaxf(r1, r3);
            float v = (mnlr / (mxlr + 1e-6f)) * (mntb / (mxtb + 1e-6f));
            v = fminf(fmaxf(v, 0.f), 1.f);
            float ct = sqrtf(v);
            cen_s += bce_logits(cenb[l], ct);
            np += 1.f;
        }
    }

    float v4[4] = {cls_s, reg_s, cen_s, np};
    blk_reduce_arr<4>(v4);
    if (threadIdx.x == 0) {
        float cls_l = v4[0] / (L * 4.f);
        float npos  = v4[3];
        float denom = fmaxf(npos, 1.f);
        float reg_l = (npos > 0.f) ? v4[1] / denom : 0.f;
        float cen_l = (npos > 0.f) ? v4[2] / denom : 0.f;
        detc[blockIdx.x] = (cls_l + reg_l + cen_l) * (1.f / (float)DET_BLOCKS);
    }
}

// ---------- final combine: all terms pre-scaled, one accumulator ----------

__global__ __launch_bounds__(256) void final_kernel(
        const float* __restrict__ segpart, const float* __restrict__ detc,
        const float* __restrict__ cls_pred, const int* __restrict__ cls_target,
        float* __restrict__ out) {
    const float seg_scale = 1.f / 33554432.f;   // B*4*512*512 (2^-25, exact)
    const float cls_scale = 0.5f / 320.f;       // W_CLS / (B*10)
    float acc = 0.f;
    for (int i = threadIdx.x; i < SEG_BLOCKS; i += 256) acc += segpart[i] * seg_scale;
    if (threadIdx.x < DET_BLOCKS) acc += detc[threadIdx.x];
    for (int e = threadIdx.x; e < NB * 10; e += 256) {
        int i = e / 10, c = e - i * 10;
        acc += cls_scale * focal_elt(cls_pred[e], (cls_target[i] == c) ? 1.f : 0.f);
    }
    float v[1] = {acc};
    blk_reduce_arr<1>(v);
    if (threadIdx.x == 0) out[0] = v[0];
}

// ---------- launch ----------

extern "C" void kernel_launch(void* const* d_in, const int* in_sizes, int n_in,
                              void* d_out, int out_size, void* d_ws, size_t ws_size,
                              hipStream_t stream) {
    const float* seg_logits = (const float*)d_in[0];
    const int*   seg_mask   = (const int*)d_in[1];
    const float* cls0 = (const float*)d_in[2];
    const float* cls1 = (const float*)d_in[3];
    const float* cls2 = (const float*)d_in[4];
    const float* reg0 = (const float*)d_in[5];
    const float* reg1 = (const float*)d_in[6];
    const float* reg2 = (const float*)d_in[7];
    const float* cen0 = (const float*)d_in[8];
    const float* cen1 = (const float*)d_in[9];
    const float* cen2 = (const float*)d_in[10];
    const float* boxes  = (const float*)d_in[11];
    const int*   labels = (const int*)d_in[12];
    const float* cls_pred   = (const float*)d_in[13];
    const int*   cls_target = (const int*)d_in[14];

    float* ws      = (float*)d_ws;
    float* segpart = ws;                 // SEG_BLOCKS floats
    float* detc    = ws + SEG_BLOCKS;    // DET_BLOCKS floats

    seg_kernel<<<SEG_BLOCKS, 256, 0, stream>>>(seg_logits, seg_mask, segpart);
    det_kernel<<<DET_BLOCKS, 256, 0, stream>>>(cls0, cls1, cls2,
                                               reg0, reg1, reg2,
                                               cen0, cen1, cen2,
                                               boxes, labels, detc);
    final_kernel<<<1, 256, 0, stream>>>(segpart, detc, cls_pred, cls_target,
                                        (float*)d_out);
}

// Round 4
// 247.552 us; speedup vs baseline: 1.3997x; 1.1765x over previous
//
#include <hip/hip_runtime.h>
#include <math.h>

#define NB 32            // batch
#define DET_BLOCKS 96    // 3 scales * 32 images
#define SEG_BLOCKS 2048  // flat-contiguous: 4096 logit quads (64 KB) each
#define TOTAL_BLOCKS (DET_BLOCKS + SEG_BLOCKS)

typedef float floatx4 __attribute__((ext_vector_type(4)));
typedef int   intx4   __attribute__((ext_vector_type(4)));

// ---------- math helpers (match reference semantics) ----------

__device__ __forceinline__ float bce_logits(float x, float y) {
    // max(x,0) - x*y + log1p(exp(-|x|))
    float a = fabsf(x);
    return fmaxf(x, 0.f) - x * y + __logf(1.f + __expf(-a));
}

__device__ __forceinline__ float bce4(floatx4 x, intx4 m) {
    return bce_logits(x.x, (float)m.x) + bce_logits(x.y, (float)m.y)
         + bce_logits(x.z, (float)m.z) + bce_logits(x.w, (float)m.w);
}

__device__ __forceinline__ float focal_elt(float x, float t) {
    // t is exactly 0.0 or 1.0 (one-hot)
    float p = 1.f / (1.f + __expf(-x));
    float ce = bce_logits(x, t);
    float p_t = (t > 0.5f) ? p : (1.f - p);
    float a_t = (t > 0.5f) ? 0.25f : 0.75f;
    float om = 1.f - p_t;
    return a_t * om * om * ce;
}

// Block reduction for N floats, blockDim.x == 256 (4 waves of 64).
template <int N>
__device__ void blk_reduce_arr(float* v) {
    __shared__ float sm[N][4];
    int lane = threadIdx.x & 63;
    int wid  = threadIdx.x >> 6;
#pragma unroll
    for (int j = 0; j < N; j++) {
        float x = v[j];
#pragma unroll
        for (int off = 32; off > 0; off >>= 1) x += __shfl_down(x, off, 64);
        if (lane == 0) sm[j][wid] = x;
    }
    __syncthreads();
    if (threadIdx.x == 0) {
#pragma unroll
        for (int j = 0; j < N; j++) {
            float s = 0.f;
#pragma unroll
            for (int w = 0; w < 4; w++) s += sm[j][w];
            v[j] = s;
        }
    }
}

// ---------- fused: det (blocks 0..95) + seg flat-contiguous (blocks 96..) ----------

__global__ __launch_bounds__(256) void fused_kernel(
        const float* __restrict__ seg_logits, const int* __restrict__ mask,
        const float* __restrict__ cls0, const float* __restrict__ cls1, const float* __restrict__ cls2,
        const float* __restrict__ reg0, const float* __restrict__ reg1, const float* __restrict__ reg2,
        const float* __restrict__ cen0, const float* __restrict__ cen1, const float* __restrict__ cen2,
        const float* __restrict__ boxes, const int* __restrict__ labels,
        float* __restrict__ segpart, float* __restrict__ detc) {

    if (blockIdx.x < DET_BLOCKS) {
        // ===== det block: one (scale, image) =====
        const int s = blockIdx.x >> 5;   // 0..2
        const int b = blockIdx.x & 31;   // 0..31
        int Wd, shift, L; float stride;
        const float *cls, *reg, *cen;
        if (s == 0)      { Wd = 64; shift = 6; L = 4096; stride = 8.f;  cls = cls0; reg = reg0; cen = cen0; }
        else if (s == 1) { Wd = 32; shift = 5; L = 1024; stride = 16.f; cls = cls1; reg = reg1; cen = cen1; }
        else             { Wd = 16; shift = 4; L = 256;  stride = 32.f; cls = cls2; reg = reg2; cen = cen2; }

        __shared__ float sx0[20], sy0[20], sx1[20], sy1[20], sar[20];
        __shared__ int   slb[20];
        if (threadIdx.x < 20) {
            int k = threadIdx.x;
            const float* bb = boxes + (b * 20 + k) * 4;
            float cx = bb[0] * 512.f, cy = bb[1] * 512.f;
            float w  = bb[2] * 512.f, h  = bb[3] * 512.f;
            float x0 = cx - 0.5f * w, y0 = cy - 0.5f * h;
            float x1 = cx + 0.5f * w, y1 = cy + 0.5f * h;
            sx0[k] = x0; sy0[k] = y0; sx1[k] = x1; sy1[k] = y1;
            sar[k] = (x1 - x0) * (y1 - y0);
            slb[k] = labels[b * 20 + k];
        }
        __syncthreads();

        const float* clsb = cls + (size_t)b * 5 * L;
        const float* regb = reg + (size_t)b * 4 * L;
        const float* cenb = cen + (size_t)b * L;
        const float inv = 1.f / stride;

        float cls_s = 0.f, reg_s = 0.f, cen_s = 0.f, np = 0.f;
        for (int l = threadIdx.x; l < L; l += 256) {
            float lx = ((l & (Wd - 1)) + 0.5f) * stride;
            float ly = ((l >> shift)   + 0.5f) * stride;
            int bk = -1; float ba = INFINITY;
            float bl = 0.f, btp = 0.f, brr = 0.f, bbt = 0.f;
#pragma unroll
            for (int k = 0; k < 20; k++) {
                float li = lx - sx0[k], ti = ly - sy0[k];
                float ri = sx1[k] - lx, bi = sy1[k] - ly;
                float mn = fminf(fminf(li, ti), fminf(ri, bi));
                if (mn > 0.f && sar[k] < ba) {   // strict '<' == first-occurrence argmin
                    ba = sar[k]; bk = k;
                    bl = li; btp = ti; brr = ri; bbt = bi;
                }
            }
            int tl = (bk >= 0) ? slb[bk] : -1;
#pragma unroll
            for (int c = 0; c < 4; c++) {
                float x = clsb[(c + 1) * L + l];   // channel 0 dropped by reference
                cls_s += focal_elt(x, (c == tl) ? 1.f : 0.f);
            }
            if (bk >= 0) {
                float r0 = bl * inv, r1 = btp * inv, r2 = brr * inv, r3 = bbt * inv;
                float d0 = regb[0 * L + l] - r0;
                float d1 = regb[1 * L + l] - r1;
                float d2 = regb[2 * L + l] - r2;
                float d3 = regb[3 * L + l] - r3;
                float a0 = fabsf(d0), a1 = fabsf(d1), a2 = fabsf(d2), a3 = fabsf(d3);
                float sl = (a0 < 1.f ? 0.5f * d0 * d0 : a0 - 0.5f)
                         + (a1 < 1.f ? 0.5f * d1 * d1 : a1 - 0.5f)
                         + (a2 < 1.f ? 0.5f * d2 * d2 : a2 - 0.5f)
                         + (a3 < 1.f ? 0.5f * d3 * d3 : a3 - 0.5f);
                reg_s += 0.25f * sl;
                float mnlr = fminf(r0, r2), mxlr = fmaxf(r0, r2);
                float mntb = fminf(r1, r3), mxtb = fmaxf(r1, r3);
                float v = (mnlr / (mxlr + 1e-6f)) * (mntb / (mxtb + 1e-6f));
                v = fminf(fmaxf(v, 0.f), 1.f);
                float ct = sqrtf(v);
                cen_s += bce_logits(cenb[l], ct);
                np += 1.f;
            }
        }

        float v4[4] = {cls_s, reg_s, cen_s, np};
        blk_reduce_arr<4>(v4);
        if (threadIdx.x == 0) {
            float cls_l = v4[0] / (L * 4.f);
            float npos  = v4[3];
            float denom = fmaxf(npos, 1.f);
            float reg_l = (npos > 0.f) ? v4[1] / denom : 0.f;
            float cen_l = (npos > 0.f) ? v4[2] / denom : 0.f;
            detc[blockIdx.x] = (cls_l + reg_l + cen_l) * (1.f / (float)DET_BLOCKS);
        }
        return;
    }

    // ===== seg block: 4096 CONTIGUOUS logit quads + matching contiguous mask =====
    // Layout experiment: 2 contiguous streams per block instead of 5 streams at
    // congruent 1-MB power-of-2 strides. seg_logits is [b][c][pix]; one plane
    // (b,c) = 65536 quads = exactly 16 blocks, so blocks never straddle planes.
    // Reference target for (b,c,pix) is mask[b,pix] for EVERY c, so the mask
    // chunk for a block is also one contiguous 64-KB run (re-read once per
    // channel; co-resident reader blocks -> L2/L3 serves the re-reads).
    const int s     = blockIdx.x - DET_BLOCKS;     // 0..2047 flat 64-KB chunk id
    const int plane = s >> 4;                      // b*4 + c
    const int b     = plane >> 2;                  // image
    const int poff  = (s & 15) << 12;              // pixel-quad offset in image

    const floatx4* Lq = (const floatx4*)seg_logits + (size_t)s * 4096;
    const intx4*   Mq = (const intx4*)mask + (size_t)b * 65536 + poff;
    const int t = threadIdx.x;

    float acc = 0.f;
#pragma unroll 2
    for (int g = 0; g < 4; g++) {
        const int base = (g << 10) + t;            // g*1024 + t
        // 8 independent contiguous dwordx4 loads, then compute
        const floatx4 x0 = Lq[base];
        const floatx4 x1 = Lq[base + 256];
        const floatx4 x2 = Lq[base + 512];
        const floatx4 x3 = Lq[base + 768];
        const intx4   m0 = Mq[base];
        const intx4   m1 = Mq[base + 256];
        const intx4   m2 = Mq[base + 512];
        const intx4   m3 = Mq[base + 768];
        acc += bce4(x0, m0);
        acc += bce4(x1, m1);
        acc += bce4(x2, m2);
        acc += bce4(x3, m3);
    }

    float v[1] = {acc};
    blk_reduce_arr<1>(v);
    if (threadIdx.x == 0) segpart[s] = v[0];
}

// ---------- final combine: all terms pre-scaled, one accumulator ----------

__global__ __launch_bounds__(256) void final_kernel(
        const float* __restrict__ segpart, const float* __restrict__ detc,
        const float* __restrict__ cls_pred, const int* __restrict__ cls_target,
        float* __restrict__ out) {
    const float seg_scale = 1.f / 33554432.f;   // B*4*512*512 (2^-25, exact)
    const float cls_scale = 0.5f / 320.f;       // W_CLS / (B*10)
    float acc = 0.f;
    for (int i = threadIdx.x; i < SEG_BLOCKS; i += 256) acc += segpart[i] * seg_scale;
    if (threadIdx.x < DET_BLOCKS) acc += detc[threadIdx.x];
    for (int e = threadIdx.x; e < NB * 10; e += 256) {
        int i = e / 10, c = e - i * 10;
        acc += cls_scale * focal_elt(cls_pred[e], (cls_target[i] == c) ? 1.f : 0.f);
    }
    float v[1] = {acc};
    blk_reduce_arr<1>(v);
    if (threadIdx.x == 0) out[0] = v[0];
}

// ---------- launch ----------

extern "C" void kernel_launch(void* const* d_in, const int* in_sizes, int n_in,
                              void* d_out, int out_size, void* d_ws, size_t ws_size,
                              hipStream_t stream) {
    const float* seg_logits = (const float*)d_in[0];
    const int*   seg_mask   = (const int*)d_in[1];
    const float* cls0 = (const float*)d_in[2];
    const float* cls1 = (const float*)d_in[3];
    const float* cls2 = (const float*)d_in[4];
    const float* reg0 = (const float*)d_in[5];
    const float* reg1 = (const float*)d_in[6];
    const float* reg2 = (const float*)d_in[7];
    const float* cen0 = (const float*)d_in[8];
    const float* cen1 = (const float*)d_in[9];
    const float* cen2 = (const float*)d_in[10];
    const float* boxes  = (const float*)d_in[11];
    const int*   labels = (const int*)d_in[12];
    const float* cls_pred   = (const float*)d_in[13];
    const int*   cls_target = (const int*)d_in[14];

    float* ws      = (float*)d_ws;
    float* segpart = ws;                 // SEG_BLOCKS floats
    float* detc    = ws + SEG_BLOCKS;    // DET_BLOCKS floats

    fused_kernel<<<TOTAL_BLOCKS, 256, 0, stream>>>(seg_logits, seg_mask,
                                                   cls0, cls1, cls2,
                                                   reg0, reg1, reg2,
                                                   cen0, cen1, cen2,
                                                   boxes, labels, segpart, detc);
    final_kernel<<<1, 256, 0, stream>>>(segpart, detc, cls_pred, cls_target,
                                        (float*)d_out);
}